// Round 1
// baseline (381.512 us; speedup 1.0000x reference)
//
#include <hip/hip_runtime.h>
#include <stdint.h>

typedef __bf16 bf16x8 __attribute__((ext_vector_type(8)));
typedef float f32x4 __attribute__((ext_vector_type(4)));
typedef unsigned short u16x8 __attribute__((ext_vector_type(8)));

#define D_MODEL 1024
#define T_SEQ 2048
#define BATCH 2
#define NHEAD 16
#define HDIM 64
#define MROWS (BATCH * T_SEQ)          // 4096
#define HEADS_TOTAL (BATCH * NHEAD)    // 32
#define QKV_ELEMS (HEADS_TOTAL * T_SEQ * HDIM)  // 4,194,304 per tensor

__device__ __forceinline__ unsigned short f32_to_bf16_rne(float f) {
    uint32_t u = __builtin_bit_cast(uint32_t, f);
    uint32_t r = (u + 0x7FFFu + ((u >> 16) & 1u)) >> 16;
    return (unsigned short)r;
}

__device__ __forceinline__ void gload_lds16(const void* g, void* l) {
    __builtin_amdgcn_global_load_lds(
        (const __attribute__((address_space(1))) void*)g,
        (__attribute__((address_space(3))) void*)l, 16, 0, 0);
}

__device__ __forceinline__ f32x4 mfma_bf16(bf16x8 a, bf16x8 b, f32x4 c) {
    return __builtin_amdgcn_mfma_f32_16x16x32_bf16(a, b, c, 0, 0, 0);
}

// ---------------- convert x: f32 -> bf16, 8 elems/thread ----------------
__global__ void k_convert(const float4* __restrict__ in, u16x8* __restrict__ out, int n8) {
    int i = blockIdx.x * 256 + threadIdx.x;
    if (i >= n8) return;
    float4 a = in[i * 2];
    float4 b = in[i * 2 + 1];
    u16x8 r;
    r[0] = f32_to_bf16_rne(a.x); r[1] = f32_to_bf16_rne(a.y);
    r[2] = f32_to_bf16_rne(a.z); r[3] = f32_to_bf16_rne(a.w);
    r[4] = f32_to_bf16_rne(b.x); r[5] = f32_to_bf16_rne(b.y);
    r[6] = f32_to_bf16_rne(b.z); r[7] = f32_to_bf16_rne(b.w);
    out[i] = r;
}

// ---------- transpose-convert: in f32 [R][C] -> out bf16 [C][R] ----------
__global__ void k_transpose_conv(const float* __restrict__ in, unsigned short* __restrict__ out,
                                 int R, int C) {
    __shared__ float tile[32][33];
    int nc = C >> 5;
    int tc0 = (blockIdx.x % nc) * 32;
    int tr0 = (blockIdx.x / nc) * 32;
    int tx = threadIdx.x & 31, ty = threadIdx.x >> 5;  // ty 0..7
#pragma unroll
    for (int i = 0; i < 4; ++i) {
        int r = ty * 4 + i;
        tile[r][tx] = in[(size_t)(tr0 + r) * C + tc0 + tx];
    }
    __syncthreads();
#pragma unroll
    for (int i = 0; i < 4; ++i) {
        int c = ty * 4 + i;
        out[(size_t)(tc0 + c) * R + tr0 + tx] = f32_to_bf16_rne(tile[tx][c]);
    }
}

// ---------------- GEMM: C[M][N] = A[M][K](bf16) @ Bt[N][K](bf16) + bias ----------------
// 128x128 tile, BK=32, 256 threads (4 waves as 2x2), 4x4 16x16x32 mfma frags per wave.
// EPI 0: scatter QKV (out = q base; k = +QKV_ELEMS; v = +2*QKV_ELEMS), Q scaled 1/8.
// EPI 1: f32 out row-major + bias.
template <int EPI>
__global__ __launch_bounds__(256) void k_gemm(const unsigned short* __restrict__ A,
                                              const unsigned short* __restrict__ Bt,
                                              const float* __restrict__ bias,
                                              void* __restrict__ outp,
                                              int M, int N, int K) {
    __shared__ __align__(16) unsigned short As[128 * 32];
    __shared__ __align__(16) unsigned short Bs[128 * 32];
    const int NB = N >> 7;
    int bm = blockIdx.x / NB, bn = blockIdx.x % NB;
    int tid = threadIdx.x;
    int lane = tid & 63, w = tid >> 6;
    int wr = w >> 1, wc = w & 1;
    int l15 = lane & 15, lg = lane >> 4;

    f32x4 acc[4][4] = {};

    const int nK = K >> 5;
    int c1 = tid, c2 = tid + 256;
    int r1 = c1 >> 2, o1 = (c1 & 3) * 8;
    int r2 = c2 >> 2, o2 = (c2 & 3) * 8;
    char* AsB = (char*)As;
    char* BsB = (char*)Bs;

    for (int kt = 0; kt < nK; ++kt) {
        if (kt) __syncthreads();
        int k0 = kt * 32;
        gload_lds16(A + (size_t)(bm * 128 + r1) * K + k0 + o1, AsB + w * 1024);
        gload_lds16(A + (size_t)(bm * 128 + r2) * K + k0 + o2, AsB + 4096 + w * 1024);
        gload_lds16(Bt + (size_t)(bn * 128 + r1) * K + k0 + o1, BsB + w * 1024);
        gload_lds16(Bt + (size_t)(bn * 128 + r2) * K + k0 + o2, BsB + 4096 + w * 1024);
        __syncthreads();  // drains vmcnt(0) -> LDS tiles ready

        bf16x8 af[4], bfr[4];
#pragma unroll
        for (int i = 0; i < 4; ++i)
            af[i] = *(const bf16x8*)(As + (wr * 64 + i * 16 + l15) * 32 + lg * 8);
#pragma unroll
        for (int j = 0; j < 4; ++j)
            bfr[j] = *(const bf16x8*)(Bs + (wc * 64 + j * 16 + l15) * 32 + lg * 8);
#pragma unroll
        for (int i = 0; i < 4; ++i)
#pragma unroll
            for (int j = 0; j < 4; ++j)
                acc[i][j] = mfma_bf16(af[i], bfr[j], acc[i][j]);
    }

    // epilogue
    if (EPI == 1) {
        float* out = (float*)outp;
#pragma unroll
        for (int jn = 0; jn < 4; ++jn) {
            int n = bn * 128 + wc * 64 + jn * 16 + l15;
            float bv = bias[n];
#pragma unroll
            for (int i = 0; i < 4; ++i) {
#pragma unroll
                for (int j = 0; j < 4; ++j) {
                    int m = bm * 128 + wr * 64 + i * 16 + lg * 4 + j;
                    out[(size_t)m * N + n] = acc[i][jn][j] + bv;
                }
            }
        }
    } else {
        unsigned short* qkv = (unsigned short*)outp;
#pragma unroll
        for (int jn = 0; jn < 4; ++jn) {
            int n = bn * 128 + wc * 64 + jn * 16 + l15;
            float bv = bias[n];
            int part = n >> 10;          // 0=q 1=k 2=v
            int cc = n & 1023;
            int h = cc >> 6, d = cc & 63;
            float scale = (part == 0) ? 0.125f : 1.0f;
            unsigned short* dst = qkv + (size_t)part * QKV_ELEMS;
#pragma unroll
            for (int i = 0; i < 4; ++i) {
#pragma unroll
                for (int j = 0; j < 4; ++j) {
                    int m = bm * 128 + wr * 64 + i * 16 + lg * 4 + j;
                    int b = m >> 11, t = m & 2047;
                    float v = (acc[i][jn][j] + bv) * scale;
                    dst[((size_t)(b * NHEAD + h) * T_SEQ + t) * HDIM + d] = f32_to_bf16_rne(v);
                }
            }
        }
    }
}

// ---------------- V transpose: [bh][t][d] -> [bh][d][t] ----------------
__global__ void k_transpose_v(const unsigned short* __restrict__ V, unsigned short* __restrict__ Vt) {
    __shared__ unsigned short tile[64][66];
    int bh = blockIdx.x >> 5;
    int t0 = (blockIdx.x & 31) * 64;
    const unsigned short* Vb = V + (size_t)bh * T_SEQ * HDIM;
    unsigned short* Vtb = Vt + (size_t)bh * HDIM * T_SEQ;
    int d = threadIdx.x & 63, tq = threadIdx.x >> 6;
#pragma unroll
    for (int r = 0; r < 16; ++r) {
        int tl = tq * 16 + r;
        tile[tl][d] = Vb[(size_t)(t0 + tl) * HDIM + d];
    }
    __syncthreads();
    int tl = threadIdx.x & 63, dq = threadIdx.x >> 6;
#pragma unroll
    for (int r = 0; r < 16; ++r) {
        int dd = dq * 16 + r;
        Vtb[(size_t)dd * T_SEQ + t0 + tl] = tile[tl][dd];
    }
}

// ---------------- flash attention ----------------
// grid = 32 bh * 32 qtiles; block = 256 (4 waves, 16 q-rows each). KBLK=32.
__global__ __launch_bounds__(256) void k_attn(const unsigned short* __restrict__ Qg,
                                              const unsigned short* __restrict__ Kg,
                                              const unsigned short* __restrict__ Vtg,
                                              unsigned short* __restrict__ Og) {
    __shared__ __align__(16) unsigned short Plds[4][16 * 32];
    int bh = blockIdx.x >> 5;
    int qt = blockIdx.x & 31;
    int tid = threadIdx.x;
    int w = tid >> 6, lane = tid & 63;
    int l15 = lane & 15, lg = lane >> 4;
    int q0 = qt * 64 + w * 16;

    const unsigned short* Qb = Qg + (size_t)bh * T_SEQ * HDIM;
    const unsigned short* Kb = Kg + (size_t)bh * T_SEQ * HDIM;
    const unsigned short* Vb = Vtg + (size_t)bh * HDIM * T_SEQ;

    bf16x8 qf[2];
    qf[0] = *(const bf16x8*)(Qb + (size_t)(q0 + l15) * HDIM + lg * 8);
    qf[1] = *(const bf16x8*)(Qb + (size_t)(q0 + l15) * HDIM + 32 + lg * 8);

    f32x4 o_acc[4] = {};
    float m_j[4] = {-INFINITY, -INFINITY, -INFINITY, -INFINITY};
    float l_j[4] = {0.f, 0.f, 0.f, 0.f};

    unsigned short* pl = Plds[w];

    for (int kt = 0; kt < T_SEQ / 32; ++kt) {
        int kv0 = kt * 32;
        f32x4 s[2] = {};
#pragma unroll
        for (int jn = 0; jn < 2; ++jn) {
            bf16x8 kf0 = *(const bf16x8*)(Kb + (size_t)(kv0 + jn * 16 + l15) * HDIM + lg * 8);
            bf16x8 kf1 = *(const bf16x8*)(Kb + (size_t)(kv0 + jn * 16 + l15) * HDIM + 32 + lg * 8);
            s[jn] = mfma_bf16(qf[0], kf0, s[jn]);
            s[jn] = mfma_bf16(qf[1], kf1, s[jn]);
        }
        // online softmax, rows owned: lg*4+j, reduce across 16 lanes (l15)
        float pscale[4];
        unsigned short pb0[4], pb1[4];
#pragma unroll
        for (int j = 0; j < 4; ++j) {
            float s0 = s[0][j], s1 = s[1][j];
            float mx = fmaxf(s0, s1);
#pragma unroll
            for (int off = 8; off >= 1; off >>= 1) mx = fmaxf(mx, __shfl_xor(mx, off));
            float mn = fmaxf(m_j[j], mx);
            float p0 = __expf(s0 - mn), p1 = __expf(s1 - mn);
            float sc = __expf(m_j[j] - mn);
            m_j[j] = mn;
            float ps = p0 + p1;
#pragma unroll
            for (int off = 8; off >= 1; off >>= 1) ps += __shfl_xor(ps, off);
            l_j[j] = l_j[j] * sc + ps;
            pscale[j] = sc;
            pb0[j] = f32_to_bf16_rne(p0);
            pb1[j] = f32_to_bf16_rne(p1);
        }
#pragma unroll
        for (int dn = 0; dn < 4; ++dn)
#pragma unroll
            for (int j = 0; j < 4; ++j) o_acc[dn][j] *= pscale[j];

        // repack P through per-wave LDS into A-fragment layout
#pragma unroll
        for (int j = 0; j < 4; ++j) {
            pl[(lg * 4 + j) * 32 + l15] = pb0[j];
            pl[(lg * 4 + j) * 32 + 16 + l15] = pb1[j];
        }
        asm volatile("s_waitcnt lgkmcnt(0)" ::: "memory");
        bf16x8 pa = *(const bf16x8*)(pl + l15 * 32 + lg * 8);
#pragma unroll
        for (int dn = 0; dn < 4; ++dn) {
            bf16x8 vf = *(const bf16x8*)(Vb + (size_t)(dn * 16 + l15) * T_SEQ + kv0 + lg * 8);
            o_acc[dn] = mfma_bf16(pa, vf, o_acc[dn]);
        }
    }

    // epilogue: O[b][t][h*64+d] bf16
    int b = bh >> 4, h = bh & 15;
#pragma unroll
    for (int dn = 0; dn < 4; ++dn) {
#pragma unroll
        for (int j = 0; j < 4; ++j) {
            int t = q0 + lg * 4 + j;
            float ov = o_acc[dn][j] / l_j[j];
            Og[((size_t)(b * T_SEQ + t)) * D_MODEL + h * HDIM + dn * 16 + l15] =
                f32_to_bf16_rne(ov);
        }
    }
}

// ---------------- launch ----------------
extern "C" void kernel_launch(void* const* d_in, const int* in_sizes, int n_in,
                              void* d_out, int out_size, void* d_ws, size_t ws_size,
                              hipStream_t stream) {
    const float* x = (const float*)d_in[0];
    const float* w_qkv = (const float*)d_in[1];
    const float* b_qkv = (const float*)d_in[2];
    const float* w_out = (const float*)d_in[3];
    const float* b_out = (const float*)d_in[4];
    float* out = (float*)d_out;
    char* ws = (char*)d_ws;

    // workspace layout (bytes)
    unsigned short* x_bf   = (unsigned short*)(ws + 0);          // 8MB, reused as Vt later
    unsigned short* wqkv_t = (unsigned short*)(ws + 8388608);    // 6MB
    unsigned short* wout_t = (unsigned short*)(ws + 14680064);   // 2MB
    unsigned short* Qb     = (unsigned short*)(ws + 16777216);   // 8MB
    unsigned short* Kb     = (unsigned short*)(ws + 25165824);   // 8MB
    unsigned short* Vb     = (unsigned short*)(ws + 33554432);   // 8MB, reused as O later
    unsigned short* Vt     = x_bf;   // alias: x_bf dead after GEMM1
    unsigned short* Ob     = Vb;     // alias: V dead after transpose

    // 1. convert x to bf16
    k_convert<<<MROWS * D_MODEL / 8 / 256, 256, 0, stream>>>((const float4*)x, (u16x8*)x_bf,
                                                             MROWS * D_MODEL / 8);
    // 2. transpose-convert weights to [N][K] bf16
    k_transpose_conv<<<(D_MODEL / 32) * (3 * D_MODEL / 32), 256, 0, stream>>>(w_qkv, wqkv_t,
                                                                              D_MODEL, 3 * D_MODEL);
    k_transpose_conv<<<(D_MODEL / 32) * (D_MODEL / 32), 256, 0, stream>>>(w_out, wout_t,
                                                                          D_MODEL, D_MODEL);
    // 3. QKV GEMM + scatter
    k_gemm<0><<<(MROWS / 128) * (3 * D_MODEL / 128), 256, 0, stream>>>(x_bf, wqkv_t, b_qkv,
                                                                       (void*)Qb, MROWS,
                                                                       3 * D_MODEL, D_MODEL);
    // 4. V transpose
    k_transpose_v<<<HEADS_TOTAL * (T_SEQ / 64), 256, 0, stream>>>(Vb, Vt);
    // 5. attention
    k_attn<<<HEADS_TOTAL * (T_SEQ / 64), 256, 0, stream>>>(Qb, Kb, Vt, Ob);
    // 6. output projection
    k_gemm<1><<<(MROWS / 128) * (D_MODEL / 128), 256, 0, stream>>>(Ob, wout_t, b_out, (void*)out,
                                                                   MROWS, D_MODEL, D_MODEL);
}

// Round 2
// 229.307 us; speedup vs baseline: 1.6638x; 1.6638x over previous
//
#include <hip/hip_runtime.h>
#include <stdint.h>

typedef __bf16 bf16x8 __attribute__((ext_vector_type(8)));
typedef float f32x4 __attribute__((ext_vector_type(4)));
typedef float f32x16 __attribute__((ext_vector_type(16)));
typedef unsigned short u16x8 __attribute__((ext_vector_type(8)));

#define D_MODEL 1024
#define T_SEQ 2048
#define BATCH 2
#define NHEAD 16
#define HDIM 64
#define MROWS (BATCH * T_SEQ)          // 4096
#define HEADS_TOTAL (BATCH * NHEAD)    // 32
#define QKV_ELEMS (HEADS_TOTAL * T_SEQ * HDIM)  // 4,194,304 per tensor

__device__ __forceinline__ unsigned short f32_to_bf16_rne(float f) {
    uint32_t u = __builtin_bit_cast(uint32_t, f);
    uint32_t r = (u + 0x7FFFu + ((u >> 16) & 1u)) >> 16;
    return (unsigned short)r;
}

__device__ __forceinline__ uint32_t pack2(float a, float b) {
    return (uint32_t)f32_to_bf16_rne(a) | ((uint32_t)f32_to_bf16_rne(b) << 16);
}

__device__ __forceinline__ void gload_lds16(const void* g, void* l) {
    __builtin_amdgcn_global_load_lds(
        (const __attribute__((address_space(1))) void*)g,
        (__attribute__((address_space(3))) void*)l, 16, 0, 0);
}

__device__ __forceinline__ f32x4 mfma_bf16(bf16x8 a, bf16x8 b, f32x4 c) {
    return __builtin_amdgcn_mfma_f32_16x16x32_bf16(a, b, c, 0, 0, 0);
}
__device__ __forceinline__ f32x16 mfma32(bf16x8 a, bf16x8 b, f32x16 c) {
    return __builtin_amdgcn_mfma_f32_32x32x16_bf16(a, b, c, 0, 0, 0);
}

// ---------------- convert x: f32 -> bf16, 8 elems/thread ----------------
__global__ void k_convert(const float4* __restrict__ in, u16x8* __restrict__ out, int n8) {
    int i = blockIdx.x * 256 + threadIdx.x;
    if (i >= n8) return;
    float4 a = in[i * 2];
    float4 b = in[i * 2 + 1];
    u16x8 r;
    r[0] = f32_to_bf16_rne(a.x); r[1] = f32_to_bf16_rne(a.y);
    r[2] = f32_to_bf16_rne(a.z); r[3] = f32_to_bf16_rne(a.w);
    r[4] = f32_to_bf16_rne(b.x); r[5] = f32_to_bf16_rne(b.y);
    r[6] = f32_to_bf16_rne(b.z); r[7] = f32_to_bf16_rne(b.w);
    out[i] = r;
}

// ---------- transpose-convert: in f32 [R][C] -> out bf16 [C][R] ----------
__global__ void k_transpose_conv(const float* __restrict__ in, unsigned short* __restrict__ out,
                                 int R, int C) {
    __shared__ float tile[32][33];
    int nc = C >> 5;
    int tc0 = (blockIdx.x % nc) * 32;
    int tr0 = (blockIdx.x / nc) * 32;
    int tx = threadIdx.x & 31, ty = threadIdx.x >> 5;  // ty 0..7
#pragma unroll
    for (int i = 0; i < 4; ++i) {
        int r = ty * 4 + i;
        tile[r][tx] = in[(size_t)(tr0 + r) * C + tc0 + tx];
    }
    __syncthreads();
#pragma unroll
    for (int i = 0; i < 4; ++i) {
        int c = ty * 4 + i;
        out[(size_t)(tc0 + c) * R + tr0 + tx] = f32_to_bf16_rne(tile[tx][c]);
    }
}

// ---------------- GEMM: C[M][N] = A[M][K](bf16) @ Bt[N][K](bf16) + bias ----------------
template <int EPI>
__global__ __launch_bounds__(256) void k_gemm(const unsigned short* __restrict__ A,
                                              const unsigned short* __restrict__ Bt,
                                              const float* __restrict__ bias,
                                              void* __restrict__ outp,
                                              int M, int N, int K) {
    __shared__ __align__(16) unsigned short As[128 * 32];
    __shared__ __align__(16) unsigned short Bs[128 * 32];
    const int NB = N >> 7;
    int bm = blockIdx.x / NB, bn = blockIdx.x % NB;
    int tid = threadIdx.x;
    int lane = tid & 63, w = tid >> 6;
    int wr = w >> 1, wc = w & 1;
    int l15 = lane & 15, lg = lane >> 4;

    f32x4 acc[4][4] = {};

    const int nK = K >> 5;
    int c1 = tid, c2 = tid + 256;
    int r1 = c1 >> 2, o1 = (c1 & 3) * 8;
    int r2 = c2 >> 2, o2 = (c2 & 3) * 8;
    char* AsB = (char*)As;
    char* BsB = (char*)Bs;

    for (int kt = 0; kt < nK; ++kt) {
        if (kt) __syncthreads();
        int k0 = kt * 32;
        gload_lds16(A + (size_t)(bm * 128 + r1) * K + k0 + o1, AsB + w * 1024);
        gload_lds16(A + (size_t)(bm * 128 + r2) * K + k0 + o2, AsB + 4096 + w * 1024);
        gload_lds16(Bt + (size_t)(bn * 128 + r1) * K + k0 + o1, BsB + w * 1024);
        gload_lds16(Bt + (size_t)(bn * 128 + r2) * K + k0 + o2, BsB + 4096 + w * 1024);
        __syncthreads();

        bf16x8 af[4], bfr[4];
#pragma unroll
        for (int i = 0; i < 4; ++i)
            af[i] = *(const bf16x8*)(As + (wr * 64 + i * 16 + l15) * 32 + lg * 8);
#pragma unroll
        for (int j = 0; j < 4; ++j)
            bfr[j] = *(const bf16x8*)(Bs + (wc * 64 + j * 16 + l15) * 32 + lg * 8);
#pragma unroll
        for (int i = 0; i < 4; ++i)
#pragma unroll
            for (int j = 0; j < 4; ++j)
                acc[i][j] = mfma_bf16(af[i], bfr[j], acc[i][j]);
    }

    if (EPI == 1) {
        float* out = (float*)outp;
#pragma unroll
        for (int jn = 0; jn < 4; ++jn) {
            int n = bn * 128 + wc * 64 + jn * 16 + l15;
            float bv = bias[n];
#pragma unroll
            for (int i = 0; i < 4; ++i) {
#pragma unroll
                for (int j = 0; j < 4; ++j) {
                    int m = bm * 128 + wr * 64 + i * 16 + lg * 4 + j;
                    out[(size_t)m * N + n] = acc[i][jn][j] + bv;
                }
            }
        }
    } else {
        unsigned short* qkv = (unsigned short*)outp;
#pragma unroll
        for (int jn = 0; jn < 4; ++jn) {
            int n = bn * 128 + wc * 64 + jn * 16 + l15;
            float bv = bias[n];
            int part = n >> 10;          // 0=q 1=k 2=v
            int cc = n & 1023;
            int h = cc >> 6, d = cc & 63;
            float scale = (part == 0) ? 0.125f : 1.0f;
            unsigned short* dst = qkv + (size_t)part * QKV_ELEMS;
#pragma unroll
            for (int i = 0; i < 4; ++i) {
#pragma unroll
                for (int j = 0; j < 4; ++j) {
                    int m = bm * 128 + wr * 64 + i * 16 + lg * 4 + j;
                    int b = m >> 11, t = m & 2047;
                    float v = (acc[i][jn][j] + bv) * scale;
                    dst[((size_t)(b * NHEAD + h) * T_SEQ + t) * HDIM + d] = f32_to_bf16_rne(v);
                }
            }
        }
    }
}

// ---------------- V transpose: [bh][t][d] -> [bh][d][t] ----------------
__global__ void k_transpose_v(const unsigned short* __restrict__ V, unsigned short* __restrict__ Vt) {
    __shared__ unsigned short tile[64][66];
    int bh = blockIdx.x >> 5;
    int t0 = (blockIdx.x & 31) * 64;
    const unsigned short* Vb = V + (size_t)bh * T_SEQ * HDIM;
    unsigned short* Vtb = Vt + (size_t)bh * HDIM * T_SEQ;
    int d = threadIdx.x & 63, tq = threadIdx.x >> 6;
#pragma unroll
    for (int r = 0; r < 16; ++r) {
        int tl = tq * 16 + r;
        tile[tl][d] = Vb[(size_t)(t0 + tl) * HDIM + d];
    }
    __syncthreads();
    int tl = threadIdx.x & 63, dq = threadIdx.x >> 6;
#pragma unroll
    for (int r = 0; r < 16; ++r) {
        int dd = dq * 16 + r;
        Vtb[(size_t)dd * T_SEQ + t0 + tl] = tile[tl][dd];
    }
}

// ---------------- flash attention, 32x32 MFMA, swapped operands ----------------
// grid = 512: xcd-pinned (bid&7)=xcd, 4 heads/xcd. block = 256 (4 waves x 32 q-rows).
// KVBLK=64, K/Vt staged in double-buffered LDS (XOR-swizzled via pre-swizzled source).
// QK^T computed as mfma(K,Q) -> S^T (q = lane&31 -> lane-local softmax).
// PV computed as mfma(Vt,P) -> O^T. P repacked via per-wave swizzled LDS buffer.
__global__ __launch_bounds__(256) void k_attn(const unsigned short* __restrict__ Qg,
                                              const unsigned short* __restrict__ Kg,
                                              const unsigned short* __restrict__ Vtg,
                                              unsigned short* __restrict__ Og) {
    __shared__ __align__(16) unsigned short Ks[2][64 * 64];
    __shared__ __align__(16) unsigned short Vs[2][64 * 64];
    __shared__ __align__(16) unsigned short Pl[4][32 * 64];

    const int NT = T_SEQ / 64;  // 32
    int bid = blockIdx.x;
    int idx = bid >> 3;
    int bh = (bid & 7) * 4 + (idx >> 4);
    int qt = idx & 15;
    int tid = threadIdx.x;
    int w = tid >> 6, lane = tid & 63;
    int l31 = lane & 31, hi = lane >> 5;
    int r7 = l31 & 7;

    const unsigned short* Qb = Qg + (size_t)bh * T_SEQ * HDIM;
    const unsigned short* Kb = Kg + (size_t)bh * T_SEQ * HDIM;
    const unsigned short* Vb = Vtg + (size_t)bh * HDIM * T_SEQ;

    int q0 = qt * 128 + w * 32;

    // Q fragments (B-operand of swapped QK^T): rows q0+l31, d = ks*16 + hi*8
    bf16x8 qf[4];
#pragma unroll
    for (int ks = 0; ks < 4; ++ks)
        qf[ks] = *(const bf16x8*)(Qb + (size_t)(q0 + l31) * HDIM + ks * 16 + hi * 8);

    f32x16 o_[2] = {};
    float m = -INFINITY, l = 0.f;
    char* pB = (char*)Pl[w];

    // stage tile `tile` into buffer `buf`: K [kv 64][d 64], Vt [d 64][kv 64],
    // linear LDS dest, source column-chunk pre-swizzled (c&7)^(row&7)
#define STAGE(tile, buf)                                                             \
    do {                                                                             \
        int kv0s = (tile) * 64;                                                      \
        _Pragma("unroll") for (int i_ = 0; i_ < 2; ++i_) {                           \
            int c_ = i_ * 256 + tid;                                                 \
            int row_ = c_ >> 3;                                                      \
            int cs_ = (c_ & 7) ^ (row_ & 7);                                         \
            gload_lds16(Kb + (size_t)(kv0s + row_) * HDIM + cs_ * 8,                 \
                        (char*)Ks[buf] + i_ * 4096 + w * 1024);                      \
            gload_lds16(Vb + (size_t)row_ * T_SEQ + kv0s + cs_ * 8,                  \
                        (char*)Vs[buf] + i_ * 4096 + w * 1024);                      \
        }                                                                            \
    } while (0)

    STAGE(0, 0);
    __syncthreads();

    for (int t = 0; t < NT; ++t) {
        int cur = t & 1;
        if (t + 1 < NT) STAGE(t + 1, cur ^ 1);

        const char* Kt = (const char*)Ks[cur];
        const char* Vt_ = (const char*)Vs[cur];

        // QK^T: S^T[kv][q], kv-halves ti, d-steps ks
        f32x16 s_[2] = {};
#pragma unroll
        for (int ti = 0; ti < 2; ++ti) {
            int row = ti * 32 + l31;
#pragma unroll
            for (int ks = 0; ks < 4; ++ks) {
                bf16x8 kf = *(const bf16x8*)(Kt + row * 128 + ((((ks << 1) | hi) ^ r7) << 4));
                s_[ti] = mfma32(kf, qf[ks], s_[ti]);
            }
        }

        // lane-local online softmax (q = l31; kv split with lane^32)
        float mx = -INFINITY;
#pragma unroll
        for (int ti = 0; ti < 2; ++ti)
#pragma unroll
            for (int rr = 0; rr < 16; ++rr) mx = fmaxf(mx, s_[ti][rr]);
        mx = fmaxf(mx, __shfl_xor(mx, 32));
        float mn = fmaxf(m, mx);
        float sc = __expf(m - mn);
        m = mn;
        float ps = 0.f;
#pragma unroll
        for (int ti = 0; ti < 2; ++ti)
#pragma unroll
            for (int rr = 0; rr < 16; ++rr) {
                float e = __expf(s_[ti][rr] - mn);
                s_[ti][rr] = e;
                ps += e;
            }
        ps += __shfl_xor(ps, 32);
        l = l * sc + ps;
#pragma unroll
        for (int rr = 0; rr < 16; ++rr) {
            o_[0][rr] *= sc;
            o_[1][rr] *= sc;
        }

        // pack P -> per-wave LDS [q 32][kv 64], swizzled chunks
#pragma unroll
        for (int ti = 0; ti < 2; ++ti)
#pragma unroll
            for (int g = 0; g < 4; ++g) {
                uint32_t w0 = pack2(s_[ti][4 * g], s_[ti][4 * g + 1]);
                uint32_t w1 = pack2(s_[ti][4 * g + 2], s_[ti][4 * g + 3]);
                int c16 = (ti * 4 + g) ^ r7;
                *(uint2*)(pB + l31 * 128 + c16 * 16 + hi * 8) = make_uint2(w0, w1);
            }
        asm volatile("s_waitcnt lgkmcnt(0)" ::: "memory");
        bf16x8 pa[4];
#pragma unroll
        for (int ks = 0; ks < 4; ++ks)
            pa[ks] = *(const bf16x8*)(pB + l31 * 128 + ((((ks << 1) | hi) ^ r7) << 4));

        // PV: O^T[d][q] += V^T[d][kv] * P^T[kv][q]
#pragma unroll
        for (int dn = 0; dn < 2; ++dn) {
            int row = dn * 32 + l31;
#pragma unroll
            for (int ks = 0; ks < 4; ++ks) {
                bf16x8 vf = *(const bf16x8*)(Vt_ + row * 128 + ((((ks << 1) | hi) ^ r7) << 4));
                o_[dn] = mfma32(vf, pa[ks], o_[dn]);
            }
        }
        __syncthreads();
    }
#undef STAGE

    // epilogue: divide by l (lane-local), transpose O^T -> O via per-wave LDS, store coalesced
    float inv = 1.0f / l;
#pragma unroll
    for (int rr = 0; rr < 16; ++rr) {
        o_[0][rr] *= inv;
        o_[1][rr] *= inv;
    }
#pragma unroll
    for (int dn = 0; dn < 2; ++dn)
#pragma unroll
        for (int g = 0; g < 4; ++g) {
            uint32_t w0 = pack2(o_[dn][4 * g], o_[dn][4 * g + 1]);
            uint32_t w1 = pack2(o_[dn][4 * g + 2], o_[dn][4 * g + 3]);
            int c16 = (dn * 4 + g) ^ r7;
            *(uint2*)(pB + l31 * 128 + c16 * 16 + hi * 8) = make_uint2(w0, w1);
        }
    asm volatile("s_waitcnt lgkmcnt(0)" ::: "memory");
    int b = bh >> 4, h = bh & 15;
#pragma unroll
    for (int i = 0; i < 4; ++i) {
        int c = i * 64 + lane;
        int row = c >> 3;   // q within wave block
        int c16l = c & 7;   // d chunk
        bf16x8 ov = *(const bf16x8*)(pB + row * 128 + ((c16l ^ (row & 7)) << 4));
        *(bf16x8*)(Og + ((size_t)(b * T_SEQ + q0 + row)) * D_MODEL + h * HDIM + c16l * 8) = ov;
    }
}

// ---------------- launch ----------------
extern "C" void kernel_launch(void* const* d_in, const int* in_sizes, int n_in,
                              void* d_out, int out_size, void* d_ws, size_t ws_size,
                              hipStream_t stream) {
    const float* x = (const float*)d_in[0];
    const float* w_qkv = (const float*)d_in[1];
    const float* b_qkv = (const float*)d_in[2];
    const float* w_out = (const float*)d_in[3];
    const float* b_out = (const float*)d_in[4];
    float* out = (float*)d_out;
    char* ws = (char*)d_ws;

    unsigned short* x_bf   = (unsigned short*)(ws + 0);          // 8MB, reused as Vt later
    unsigned short* wqkv_t = (unsigned short*)(ws + 8388608);    // 6MB
    unsigned short* wout_t = (unsigned short*)(ws + 14680064);   // 2MB
    unsigned short* Qb     = (unsigned short*)(ws + 16777216);   // 8MB
    unsigned short* Kb     = (unsigned short*)(ws + 25165824);   // 8MB
    unsigned short* Vb     = (unsigned short*)(ws + 33554432);   // 8MB, reused as O later
    unsigned short* Vt     = x_bf;   // alias: x_bf dead after GEMM1
    unsigned short* Ob     = Vb;     // alias: V dead after transpose

    k_convert<<<MROWS * D_MODEL / 8 / 256, 256, 0, stream>>>((const float4*)x, (u16x8*)x_bf,
                                                             MROWS * D_MODEL / 8);
    k_transpose_conv<<<(D_MODEL / 32) * (3 * D_MODEL / 32), 256, 0, stream>>>(w_qkv, wqkv_t,
                                                                              D_MODEL, 3 * D_MODEL);
    k_transpose_conv<<<(D_MODEL / 32) * (D_MODEL / 32), 256, 0, stream>>>(w_out, wout_t,
                                                                          D_MODEL, D_MODEL);
    k_gemm<0><<<(MROWS / 128) * (3 * D_MODEL / 128), 256, 0, stream>>>(x_bf, wqkv_t, b_qkv,
                                                                       (void*)Qb, MROWS,
                                                                       3 * D_MODEL, D_MODEL);
    k_transpose_v<<<HEADS_TOTAL * (T_SEQ / 64), 256, 0, stream>>>(Vb, Vt);
    k_attn<<<512, 256, 0, stream>>>(Qb, Kb, Vt, Ob);
    k_gemm<1><<<(MROWS / 128) * (D_MODEL / 128), 256, 0, stream>>>(Ob, wout_t, b_out, (void*)out,
                                                                   MROWS, D_MODEL, D_MODEL);
}